// Round 11
// baseline (297.122 us; speedup 1.0000x reference)
//
#include <hip/hip_runtime.h>
#include <stdint.h>

// Problem constants
#define SEQ   4096
#define DIMM  512
#define HDIM  64
#define NH    8
#define ROWS  8192          // B*N = 2*4096
#define QKVN  1536          // 3*DIM

typedef __attribute__((ext_vector_type(8))) __bf16 bf16x8;   // K=32 MFMA A/B frag
typedef __attribute__((ext_vector_type(4))) __bf16 bf16x4;   // K=16 MFMA A/B frag
typedef __attribute__((ext_vector_type(4))) short  shortx4;
typedef __attribute__((ext_vector_type(4))) float  f32x4;    // MFMA C/D frag
typedef __attribute__((ext_vector_type(2))) uint32_t u32x2;

// fp32 -> bf16 (RNE), storage as uint16_t bit pattern
__device__ __forceinline__ uint16_t f2bfu(float f) {
  uint32_t u = __builtin_bit_cast(uint32_t, f);
  return (uint16_t)((u + 0x7FFFu + ((u >> 16) & 1u)) >> 16);
}

__device__ __forceinline__ f32x4 mfma16(bf16x8 a, bf16x8 b, f32x4 c) {
  return __builtin_amdgcn_mfma_f32_16x16x32_bf16(a, b, c, 0, 0, 0);
}

// 16x16x16 bf16 MFMA (HW-verified R10): A[m=l16][k=quad*4+j],
// B[k=quad*4+j][n=l16] == C-frag layout -> exp'd S^T feeds PV from registers.
__device__ __forceinline__ f32x4 mfma16x16(bf16x4 a, bf16x4 b, f32x4 c) {
#if __has_builtin(__builtin_amdgcn_mfma_f32_16x16x16_bf16)
  return __builtin_amdgcn_mfma_f32_16x16x16_bf16(a, b, c, 0, 0, 0);
#else
  return __builtin_amdgcn_mfma_f32_16x16x16bf16_1k(
      __builtin_bit_cast(shortx4, a), __builtin_bit_cast(shortx4, b), c, 0, 0, 0);
#endif
}

#if __has_builtin(__builtin_amdgcn_exp2f)
#define EXP2F(x) __builtin_amdgcn_exp2f(x)
#else
#define EXP2F(x) exp2f(x)
#endif

// async global->LDS, 16B per lane. LDS dest is wave-uniform base + lane*16;
// the GLOBAL address is per-lane free -> we use it to store XOR-swizzled tiles.
__device__ __forceinline__ void gld16(const void* g, void* l) {
  __builtin_amdgcn_global_load_lds(
      (const __attribute__((address_space(1))) uint32_t*)g,
      (__attribute__((address_space(3))) uint32_t*)l, 16, 0, 0);
}

// ---------------------------------------------------------------------------
// Kernel 1: fp32 -> bf16 conversion of x, w_qkv, w_proj (one grid, 3 segments)
// ---------------------------------------------------------------------------
#define X4  (ROWS * DIMM / 4)    // 1048576
#define Q4  (QKVN * DIMM / 4)    // 196608
#define P4  (DIMM * DIMM / 4)    // 65536

__global__ __launch_bounds__(256) void cvt_kernel(
    const float* __restrict__ x, const float* __restrict__ wq,
    const float* __restrict__ wp, uint16_t* __restrict__ xb,
    uint16_t* __restrict__ wqb, uint16_t* __restrict__ wpb) {
  int idx = blockIdx.x * 256 + threadIdx.x;    // float4 index
  const float* src; uint16_t* dst; int i4;
  if (idx < X4)            { src = x;  dst = xb;  i4 = idx; }
  else if (idx < X4 + Q4)  { src = wq; dst = wqb; i4 = idx - X4; }
  else                     { src = wp; dst = wpb; i4 = idx - X4 - Q4; }
  float4 v = ((const float4*)src)[i4];
  ushort4 o;
  o.x = f2bfu(v.x); o.y = f2bfu(v.y); o.z = f2bfu(v.z); o.w = f2bfu(v.w);
  ((ushort4*)dst)[i4] = o;
}

// ---------------------------------------------------------------------------
// Shared GEMM core: C[128x128] = A[128xK] * B[128xK]^T  (both row-major, K=512)
// 256 threads = 4 waves in 2x2, each wave 64x64 via 4x4 MFMA frags.
// acc[i][j] frag: C[row = A-row][col = B-row]. bm/bn passed explicitly so
// callers can flatten/partition their grids.
// ---------------------------------------------------------------------------
__device__ __forceinline__ void gemm_core(
    const uint16_t* __restrict__ A, const uint16_t* __restrict__ B,
    uint16_t* As, uint16_t* Bs, f32x4 acc[4][4], int bm, int bn) {
  const int tid = threadIdx.x;
  const int lane = tid & 63, wave = tid >> 6;
  const int quad = lane >> 4, l16 = lane & 15;
  const int wr = (wave & 1) * 64, wc = (wave >> 1) * 64;
  const int sw = (l16 >> 1) & 3;               // read-side swizzle key

  for (int kt = 0; kt < DIMM / 32; ++kt) {
#pragma unroll
    for (int it = 0; it < 2; ++it) {
      int L = it * 256 + tid;
      int r = L >> 2, c = L & 3;
      int gc = c ^ ((r >> 1) & 3);
      int ldsoff = (it * 256 + (tid & ~63)) * 16; // wave-uniform base
      gld16((const char*)A + ((size_t)(bm * 128 + r) * DIMM + kt * 32) * 2 + gc * 16,
            (char*)As + ldsoff);
      gld16((const char*)B + ((size_t)(bn * 128 + r) * DIMM + kt * 32) * 2 + gc * 16,
            (char*)Bs + ldsoff);
    }
    __syncthreads();
    bf16x8 af[4], bfr[4];
#pragma unroll
    for (int i = 0; i < 4; ++i)
      af[i] = *(const bf16x8*)(As + (wr + i * 16 + l16) * 32 + ((quad ^ sw) * 8));
#pragma unroll
    for (int j = 0; j < 4; ++j)
      bfr[j] = *(const bf16x8*)(Bs + (wc + j * 16 + l16) * 32 + ((quad ^ sw) * 8));
#pragma unroll
    for (int i = 0; i < 4; ++i)
#pragma unroll
      for (int j = 0; j < 4; ++j)
        acc[i][j] = mfma16(af[i], bfr[j], acc[i][j]);
    __syncthreads();
  }
}

// ---------------------------------------------------------------------------
// Kernel 2: merged QKV GEMM. Blocks 0..511: QK in C^T orientation
// (C^T[jc][m] = W_qk · X^T, lane's 4 regs = 4 consecutive hd -> ushort4);
// blocks 512..767: V in normal orientation (4 regs = 4 consecutive n ->
// ushort4 into transposed vt). Branch is block-uniform.
// 768 blocks -> 3 blocks/CU with __launch_bounds__(256,3).
// ---------------------------------------------------------------------------
__global__ __launch_bounds__(256, 3) void qkv_gemm2(
    const uint16_t* __restrict__ xb, const uint16_t* __restrict__ wqb,
    uint16_t* __restrict__ qd, uint16_t* __restrict__ kd,
    uint16_t* __restrict__ vt) {
  __shared__ __align__(16) uint16_t As[128 * 32];
  __shared__ __align__(16) uint16_t Bs[128 * 32];
  f32x4 acc[4][4];
#pragma unroll
  for (int i = 0; i < 4; ++i)
#pragma unroll
    for (int j = 0; j < 4; ++j) acc[i][j] = f32x4{0.f, 0.f, 0.f, 0.f};

  const int lane = threadIdx.x & 63, wave = threadIdx.x >> 6;
  const int quad = lane >> 4, l16 = lane & 15;
  const int wr = (wave & 1) * 64, wc = (wave >> 1) * 64;
  const int blk = blockIdx.x;

  if (blk < 512) {                      // ---- QK part, C^T orientation
    int bm = blk & 7, bn = blk >> 3;    // bm: jc-tile 0..7, bn: m-tile 0..63
    gemm_core(wqb, xb, As, Bs, acc, bm, bn);
    const float qscale = 0.125f * 1.44269504f; // fold log2(e) for exp2 softmax
    const bool isq = (bm < 4);
    uint16_t* dst = isq ? qd : kd;
    const float s = isq ? qscale : 1.0f;
#pragma unroll
    for (int i = 0; i < 4; ++i) {
      int jc0 = bm * 128 + wr + i * 16 + quad * 4;   // 4 consecutive jc
      int h = (jc0 >> 6) & 7, hd = jc0 & 63;         // hd % 4 == 0
#pragma unroll
      for (int j = 0; j < 4; ++j) {
        int m = bn * 128 + wc + j * 16 + l16;
        int b = m >> 12, n = m & 4095;
        int bh = (b << 3) | h;
        ushort4 pk;
        pk.x = f2bfu(acc[i][j][0] * s); pk.y = f2bfu(acc[i][j][1] * s);
        pk.z = f2bfu(acc[i][j][2] * s); pk.w = f2bfu(acc[i][j][3] * s);
        *(ushort4*)(dst + ((size_t)bh * SEQ + n) * HDIM + hd) = pk;
      }
    }
  } else {                              // ---- V part, normal orientation
    int idx = blk - 512;
    int bm = idx >> 2, bn = idx & 3;    // bm: m-tile 0..63, bn: col-tile 0..3
    gemm_core(xb, wqb + 1024 * DIMM, As, Bs, acc, bm, bn);
#pragma unroll
    for (int i = 0; i < 4; ++i) {
      int m0 = bm * 128 + wr + i * 16 + quad * 4;    // 4 consecutive n
      int b = m0 >> 12, n0 = m0 & 4095;
#pragma unroll
      for (int j = 0; j < 4; ++j) {
        int jcl = bn * 128 + wc + j * 16 + l16;      // 0..511 within v region
        int h = (jcl >> 6) & 7, hd = jcl & 63;
        int bh = (b << 3) | h;
        ushort4 pk;
        pk.x = f2bfu(acc[i][j][0]); pk.y = f2bfu(acc[i][j][1]);
        pk.z = f2bfu(acc[i][j][2]); pk.w = f2bfu(acc[i][j][3]);
        *(ushort4*)(vt + ((size_t)bh * HDIM + hd) * SEQ + n0) = pk;
      }
    }
  }
}

// ---------------------------------------------------------------------------
// Kernel 3: flash attention, S^T + register-P (R10, HW-verified), now with
// 256-KEY TILES: kt iterations 32 -> 16, halving the vmcnt-drained barriers.
//   Ks [256][64] 32KB (chunk c^=(row&7)); Vs [64][256] 32KB (c^=(row&31)).
//   pair = wave>>1 owns 32 q-rows; khalf = wave&1 takes 128 keys of each tile.
//   Per jh (8): QK (4 K=32 MFMA) -> exp2+pack in regs -> PV (8 K=16 MFMA).
// Pair-merge O buffer ALIASED onto Ks after the loop (trailing barrier).
// LDS = 32K + 32K + Lb 2K = 66K -> 2 blocks/CU, 16 waves/CU.
// 1D grid, bh = blk & 15 -> XCD-local L2 (R9-verified, FETCH 70->12MB).
// ---------------------------------------------------------------------------
__global__ __launch_bounds__(512, 4) void attn_kernel(
    const uint16_t* __restrict__ qd, const uint16_t* __restrict__ kd,
    const uint16_t* __restrict__ vt, uint16_t* __restrict__ ao) {
  __shared__ __align__(16) uint16_t Ks[256 * 64];    // 32 KB (aliased as Om later)
  __shared__ __align__(16) uint16_t Vs[64 * 256];    // 32 KB
  __shared__ __align__(16) float2 Lb[4][64];         // pair-merge lsum, 2KB

  const int tid = threadIdx.x, lane = tid & 63, wave = tid >> 6;  // wave 0..7
  const int quad = lane >> 4, l16 = lane & 15;
  const int pair = wave >> 1, khalf = wave & 1;
  const int qt = blockIdx.x >> 4, bh = blockIdx.x & 15;   // XCD-local bh
  const size_t base_qk = (size_t)bh * SEQ * HDIM;    // [bh][n][d]
  const size_t base_v  = (size_t)bh * HDIM * SEQ;    // [bh][d][n]
  const int sw7 = l16 & 7;

  // Q fragments straight from global (one-time, L2-resident): B-op of K·Q^T
  bf16x8 qf[2][2];
#pragma unroll
  for (int it2 = 0; it2 < 2; ++it2)
#pragma unroll
    for (int kh = 0; kh < 2; ++kh)
      qf[it2][kh] = *(const bf16x8*)(qd + base_qk +
          (size_t)(qt * 128 + pair * 32 + it2 * 16 + l16) * HDIM + kh * 32 + quad * 8);

  f32x4 O[2][4];            // partial over this wave's keys
  float lsum[2] = {0.f, 0.f};
#pragma unroll
  for (int a = 0; a < 2; ++a)
#pragma unroll
    for (int d = 0; d < 4; ++d) O[a][d] = f32x4{0.f, 0.f, 0.f, 0.f};

  for (int kt = 0; kt < SEQ / 256; ++kt) {
    // stage K [256][64] and Vt [64][256] (4096 chunks, 8 per thread), swizzled
#pragma unroll
    for (int it = 0; it < 4; ++it) {
      int L = it * 512 + tid;
      int ldsoff = (it * 512 + (tid & ~63)) * 16;
      int rk = L >> 3, ck = L & 7;
      int gck = ck ^ (rk & 7);
      gld16((const char*)kd + (base_qk + (size_t)(kt * 256 + rk) * HDIM) * 2 + gck * 16,
            (char*)Ks + ldsoff);
      int rv = L >> 5, cv = L & 31;
      int gcv = cv ^ (rv & 31);
      gld16((const char*)vt + (base_v + (size_t)rv * SEQ + (size_t)kt * 256) * 2 + gcv * 16,
            (char*)Vs + ldsoff);
    }
    __syncthreads();

    // per 16-key block: QK -> exp2/pack -> PV, all in registers
#pragma unroll
    for (int jh = 0; jh < 8; ++jh) {
      int jf = khalf * 8 + jh;
      const uint16_t* krow = Ks + (jf * 16 + l16) * 64;   // row&7 == sw7
      bf16x8 kf0 = *(const bf16x8*)(krow + ((quad ^ sw7) * 8));
      bf16x8 kf1 = *(const bf16x8*)(krow + (((4 + quad) ^ sw7) * 8));
      bf16x4 pb[2];
#pragma unroll
      for (int it2 = 0; it2 < 2; ++it2) {
        f32x4 s = f32x4{0.f, 0.f, 0.f, 0.f};
        s = mfma16(kf0, qf[it2][0], s);
        s = mfma16(kf1, qf[it2][1], s);
        float p0 = EXP2F(s[0]);
        float p1 = EXP2F(s[1]);
        float p2 = EXP2F(s[2]);
        float p3 = EXP2F(s[3]);
        lsum[it2] += (p0 + p1) + (p2 + p3);
        uint32_t a0 = __builtin_bit_cast(uint32_t, p0) + 0x8000u;
        uint32_t a1 = __builtin_bit_cast(uint32_t, p1) + 0x8000u;
        uint32_t a2 = __builtin_bit_cast(uint32_t, p2) + 0x8000u;
        uint32_t a3 = __builtin_bit_cast(uint32_t, p3) + 0x8000u;
        u32x2 pk;
        pk.x = (a0 >> 16) | (a1 & 0xFFFF0000u);   // [bf16(p0), bf16(p1)]
        pk.y = (a2 >> 16) | (a3 & 0xFFFF0000u);   // [bf16(p2), bf16(p3)]
        pb[it2] = __builtin_bit_cast(bf16x4, pk);
      }
      // PV A-frag: V^T[dl*16+l16][khalf*128 + jh*16 + quad*4 + j] (b64)
      // Vs row = 512B = 32 chunks; slot = gchunk ^ (row & 31).
      int c = khalf * 16 + jh * 2 + (quad >> 1);
#pragma unroll
      for (int dl = 0; dl < 4; ++dl) {
        int rowkey = ((dl & 1) << 4) | l16;     // (dl*16 + l16) & 31
        bf16x4 va = *(const bf16x4*)((const char*)Vs + (dl * 16 + l16) * 512 +
                                     ((c ^ rowkey) * 16) + (quad & 1) * 8);
#pragma unroll
        for (int it2 = 0; it2 < 2; ++it2)
          O[it2][dl] = mfma16x16(va, pb[it2], O[it2][dl]);
      }
    }
    __syncthreads();
  }

  // merge partial O / lsum across the wave pair; O buffer aliases Ks (safe:
  // all waves passed the trailing barrier after the last Ks read)
  f32x4* Om = (f32x4*)Ks;                       // [4][8][64] = 32 KB
  if (!(wave & 1)) {
#pragma unroll
    for (int it2 = 0; it2 < 2; ++it2)
#pragma unroll
      for (int dl = 0; dl < 4; ++dl)
        Om[(pair * 8 + it2 * 4 + dl) * 64 + lane] = O[it2][dl];
    Lb[pair][lane] = make_float2(lsum[0], lsum[1]);
  }
  __syncthreads();
  if (wave & 1) {
    float2 lp = Lb[pair][lane];
    lsum[0] += lp.x; lsum[1] += lp.y;
#pragma unroll
    for (int it2 = 0; it2 < 2; ++it2)
#pragma unroll
      for (int dl = 0; dl < 4; ++dl)
        O[it2][dl] += Om[(pair * 8 + it2 * 4 + dl) * 64 + lane];

    const int b = bh >> 3, h = bh & 7;
#pragma unroll
    for (int it2 = 0; it2 < 2; ++it2) {
      float l = lsum[it2];
      l += __shfl_xor(l, 16);
      l += __shfl_xor(l, 32);
      float inv = 1.0f / l;
      int q = qt * 128 + pair * 32 + it2 * 16 + l16;
      size_t rowbase = ((size_t)(b * SEQ + q)) * DIMM + h * HDIM;
#pragma unroll
      for (int dl = 0; dl < 4; ++dl) {
        ushort4 pk;
        pk.x = f2bfu(O[it2][dl][0] * inv);
        pk.y = f2bfu(O[it2][dl][1] * inv);
        pk.z = f2bfu(O[it2][dl][2] * inv);
        pk.w = f2bfu(O[it2][dl][3] * inv);
        *(ushort4*)(ao + rowbase + dl * 16 + quad * 4) = pk;
      }
    }
  }
}

// ---------------------------------------------------------------------------
// Kernel 4: output projection in C^T orientation: C^T[jc][m] = W_p · AO^T.
// Lane's 4 regs = 4 consecutive out-cols -> float4 store with float4 bias.
// Grid (4, 64).
// ---------------------------------------------------------------------------
__global__ __launch_bounds__(256, 2) void proj_gemm(
    const uint16_t* __restrict__ ao, const uint16_t* __restrict__ wpb,
    const float* __restrict__ bprj, float* __restrict__ out) {
  __shared__ __align__(16) uint16_t As[128 * 32];
  __shared__ __align__(16) uint16_t Bs[128 * 32];
  f32x4 acc[4][4];
#pragma unroll
  for (int i = 0; i < 4; ++i)
#pragma unroll
    for (int j = 0; j < 4; ++j) acc[i][j] = f32x4{0.f, 0.f, 0.f, 0.f};

  gemm_core(wpb, ao, As, Bs, acc, blockIdx.x, blockIdx.y);  // acc rows are jc

  const int lane = threadIdx.x & 63, wave = threadIdx.x >> 6;
  const int quad = lane >> 4, l16 = lane & 15;
  const int wr = (wave & 1) * 64, wc = (wave >> 1) * 64;
#pragma unroll
  for (int i = 0; i < 4; ++i) {
    int jc0 = blockIdx.x * 128 + wr + i * 16 + quad * 4;  // 4 consecutive cols
    float4 b4 = *(const float4*)(bprj + jc0);
#pragma unroll
    for (int j = 0; j < 4; ++j) {
      int m = blockIdx.y * 128 + wc + j * 16 + l16;
      float4 o;
      o.x = acc[i][j][0] + b4.x; o.y = acc[i][j][1] + b4.y;
      o.z = acc[i][j][2] + b4.z; o.w = acc[i][j][3] + b4.w;
      *(float4*)(out + (size_t)m * DIMM + jc0) = o;
    }
  }
}

// ---------------------------------------------------------------------------
extern "C" void kernel_launch(void* const* d_in, const int* in_sizes, int n_in,
                              void* d_out, int out_size, void* d_ws, size_t ws_size,
                              hipStream_t stream) {
  const float* x     = (const float*)d_in[0];
  const float* wqkv  = (const float*)d_in[1];
  const float* wproj = (const float*)d_in[2];
  const float* bproj = (const float*)d_in[3];

  char* ws = (char*)d_ws;
  uint16_t* xb  = (uint16_t*)(ws + 0);          //  8,388,608  x bf16 [8192][512]
  uint16_t* wqb = (uint16_t*)(ws + 8388608);    //  1,572,864  w_qkv bf16 [1536][512]
  uint16_t* wpb = (uint16_t*)(ws + 9961472);    //    524,288  w_proj bf16 [512][512]
  uint16_t* qd  = (uint16_t*)(ws + 10485760);   //  8,388,608  q bf16 [16][4096][64] (scaled)
  uint16_t* kd  = (uint16_t*)(ws + 18874368);   //  8,388,608  k bf16 [16][4096][64]
  uint16_t* vt  = (uint16_t*)(ws + 27262976);   //  8,388,608  v bf16 [16][64][4096]
  uint16_t* ao  = (uint16_t*)(ws + 35651584);   //  8,388,608  attn out bf16 [8192][512]

  cvt_kernel<<<(X4 + Q4 + P4) / 256, 256, 0, stream>>>(x, wqkv, wproj, xb, wqb, wpb);
  qkv_gemm2<<<768, 256, 0, stream>>>(xb, wqb, qd, kd, vt);
  attn_kernel<<<512, 512, 0, stream>>>(qd, kd, vt, ao);
  proj_gemm<<<dim3(4, 64), 256, 0, stream>>>(ao, wpb, bproj, (float*)d_out);
}

// Round 12
// 197.810 us; speedup vs baseline: 1.5021x; 1.5021x over previous
//
#include <hip/hip_runtime.h>
#include <stdint.h>

// Problem constants
#define SEQ   4096
#define DIMM  512
#define HDIM  64
#define NH    8
#define ROWS  8192          // B*N = 2*4096
#define QKVN  1536          // 3*DIM

typedef __attribute__((ext_vector_type(8))) __bf16 bf16x8;   // K=32 MFMA A/B frag
typedef __attribute__((ext_vector_type(4))) __bf16 bf16x4;   // K=16 MFMA A/B frag
typedef __attribute__((ext_vector_type(4))) short  shortx4;
typedef __attribute__((ext_vector_type(4))) float  f32x4;    // MFMA C/D frag
typedef __attribute__((ext_vector_type(2))) uint32_t u32x2;

// fp32 -> bf16 (RNE), storage as uint16_t bit pattern
__device__ __forceinline__ uint16_t f2bfu(float f) {
  uint32_t u = __builtin_bit_cast(uint32_t, f);
  return (uint16_t)((u + 0x7FFFu + ((u >> 16) & 1u)) >> 16);
}

__device__ __forceinline__ f32x4 mfma16(bf16x8 a, bf16x8 b, f32x4 c) {
  return __builtin_amdgcn_mfma_f32_16x16x32_bf16(a, b, c, 0, 0, 0);
}

// 16x16x16 bf16 MFMA (HW-verified R10): A[m=l16][k=quad*4+j],
// B[k=quad*4+j][n=l16] == C-frag layout -> exp'd S^T feeds PV from registers.
__device__ __forceinline__ f32x4 mfma16x16(bf16x4 a, bf16x4 b, f32x4 c) {
#if __has_builtin(__builtin_amdgcn_mfma_f32_16x16x16_bf16)
  return __builtin_amdgcn_mfma_f32_16x16x16_bf16(a, b, c, 0, 0, 0);
#else
  return __builtin_amdgcn_mfma_f32_16x16x16bf16_1k(
      __builtin_bit_cast(shortx4, a), __builtin_bit_cast(shortx4, b), c, 0, 0, 0);
#endif
}

#if __has_builtin(__builtin_amdgcn_exp2f)
#define EXP2F(x) __builtin_amdgcn_exp2f(x)
#else
#define EXP2F(x) exp2f(x)
#endif

// async global->LDS, 16B per lane. LDS dest is wave-uniform base + lane*16;
// the GLOBAL address is per-lane free -> we use it to store XOR-swizzled tiles.
__device__ __forceinline__ void gld16(const void* g, void* l) {
  __builtin_amdgcn_global_load_lds(
      (const __attribute__((address_space(1))) uint32_t*)g,
      (__attribute__((address_space(3))) uint32_t*)l, 16, 0, 0);
}

// ---------------------------------------------------------------------------
// Kernel 1: fp32 -> bf16 conversion of x, w_qkv, w_proj (one grid, 3 segments)
// ---------------------------------------------------------------------------
#define X4  (ROWS * DIMM / 4)    // 1048576
#define Q4  (QKVN * DIMM / 4)    // 196608
#define P4  (DIMM * DIMM / 4)    // 65536

__global__ __launch_bounds__(256) void cvt_kernel(
    const float* __restrict__ x, const float* __restrict__ wq,
    const float* __restrict__ wp, uint16_t* __restrict__ xb,
    uint16_t* __restrict__ wqb, uint16_t* __restrict__ wpb) {
  int idx = blockIdx.x * 256 + threadIdx.x;    // float4 index
  const float* src; uint16_t* dst; int i4;
  if (idx < X4)            { src = x;  dst = xb;  i4 = idx; }
  else if (idx < X4 + Q4)  { src = wq; dst = wqb; i4 = idx - X4; }
  else                     { src = wp; dst = wpb; i4 = idx - X4 - Q4; }
  float4 v = ((const float4*)src)[i4];
  ushort4 o;
  o.x = f2bfu(v.x); o.y = f2bfu(v.y); o.z = f2bfu(v.z); o.w = f2bfu(v.w);
  ((ushort4*)dst)[i4] = o;
}

// ---------------------------------------------------------------------------
// Shared GEMM core: C[128x128] = A[128xK] * B[128xK]^T  (both row-major, K=512)
// 256 threads = 4 waves in 2x2, each wave 64x64 via 4x4 MFMA frags.
// acc[i][j] frag: C[row = A-row][col = B-row]. bm/bn passed explicitly so
// callers can flatten/partition their grids.
// ---------------------------------------------------------------------------
__device__ __forceinline__ void gemm_core(
    const uint16_t* __restrict__ A, const uint16_t* __restrict__ B,
    uint16_t* As, uint16_t* Bs, f32x4 acc[4][4], int bm, int bn) {
  const int tid = threadIdx.x;
  const int lane = tid & 63, wave = tid >> 6;
  const int quad = lane >> 4, l16 = lane & 15;
  const int wr = (wave & 1) * 64, wc = (wave >> 1) * 64;
  const int sw = (l16 >> 1) & 3;               // read-side swizzle key

  for (int kt = 0; kt < DIMM / 32; ++kt) {
#pragma unroll
    for (int it = 0; it < 2; ++it) {
      int L = it * 256 + tid;
      int r = L >> 2, c = L & 3;
      int gc = c ^ ((r >> 1) & 3);
      int ldsoff = (it * 256 + (tid & ~63)) * 16; // wave-uniform base
      gld16((const char*)A + ((size_t)(bm * 128 + r) * DIMM + kt * 32) * 2 + gc * 16,
            (char*)As + ldsoff);
      gld16((const char*)B + ((size_t)(bn * 128 + r) * DIMM + kt * 32) * 2 + gc * 16,
            (char*)Bs + ldsoff);
    }
    __syncthreads();
    bf16x8 af[4], bfr[4];
#pragma unroll
    for (int i = 0; i < 4; ++i)
      af[i] = *(const bf16x8*)(As + (wr + i * 16 + l16) * 32 + ((quad ^ sw) * 8));
#pragma unroll
    for (int j = 0; j < 4; ++j)
      bfr[j] = *(const bf16x8*)(Bs + (wc + j * 16 + l16) * 32 + ((quad ^ sw) * 8));
#pragma unroll
    for (int i = 0; i < 4; ++i)
#pragma unroll
      for (int j = 0; j < 4; ++j)
        acc[i][j] = mfma16(af[i], bfr[j], acc[i][j]);
    __syncthreads();
  }
}

// ---------------------------------------------------------------------------
// Kernel 2: merged QKV GEMM. Blocks 0..511: QK in C^T orientation
// (C^T[jc][m] = W_qk · X^T, lane's 4 regs = 4 consecutive hd -> ushort4);
// blocks 512..767: V in normal orientation (4 regs = 4 consecutive n ->
// ushort4 into transposed vt). Branch is block-uniform.
// 768 blocks -> 3 blocks/CU with __launch_bounds__(256,3).
// ---------------------------------------------------------------------------
__global__ __launch_bounds__(256, 3) void qkv_gemm2(
    const uint16_t* __restrict__ xb, const uint16_t* __restrict__ wqb,
    uint16_t* __restrict__ qd, uint16_t* __restrict__ kd,
    uint16_t* __restrict__ vt) {
  __shared__ __align__(16) uint16_t As[128 * 32];
  __shared__ __align__(16) uint16_t Bs[128 * 32];
  f32x4 acc[4][4];
#pragma unroll
  for (int i = 0; i < 4; ++i)
#pragma unroll
    for (int j = 0; j < 4; ++j) acc[i][j] = f32x4{0.f, 0.f, 0.f, 0.f};

  const int lane = threadIdx.x & 63, wave = threadIdx.x >> 6;
  const int quad = lane >> 4, l16 = lane & 15;
  const int wr = (wave & 1) * 64, wc = (wave >> 1) * 64;
  const int blk = blockIdx.x;

  if (blk < 512) {                      // ---- QK part, C^T orientation
    int bm = blk & 7, bn = blk >> 3;    // bm: jc-tile 0..7, bn: m-tile 0..63
    gemm_core(wqb, xb, As, Bs, acc, bm, bn);
    const float qscale = 0.125f * 1.44269504f; // fold log2(e) for exp2 softmax
    const bool isq = (bm < 4);
    uint16_t* dst = isq ? qd : kd;
    const float s = isq ? qscale : 1.0f;
#pragma unroll
    for (int i = 0; i < 4; ++i) {
      int jc0 = bm * 128 + wr + i * 16 + quad * 4;   // 4 consecutive jc
      int h = (jc0 >> 6) & 7, hd = jc0 & 63;         // hd % 4 == 0
#pragma unroll
      for (int j = 0; j < 4; ++j) {
        int m = bn * 128 + wc + j * 16 + l16;
        int b = m >> 12, n = m & 4095;
        int bh = (b << 3) | h;
        ushort4 pk;
        pk.x = f2bfu(acc[i][j][0] * s); pk.y = f2bfu(acc[i][j][1] * s);
        pk.z = f2bfu(acc[i][j][2] * s); pk.w = f2bfu(acc[i][j][3] * s);
        *(ushort4*)(dst + ((size_t)bh * SEQ + n) * HDIM + hd) = pk;
      }
    }
  } else {                              // ---- V part, normal orientation
    int idx = blk - 512;
    int bm = idx >> 2, bn = idx & 3;    // bm: m-tile 0..63, bn: col-tile 0..3
    gemm_core(xb, wqb + 1024 * DIMM, As, Bs, acc, bm, bn);
#pragma unroll
    for (int i = 0; i < 4; ++i) {
      int m0 = bm * 128 + wr + i * 16 + quad * 4;    // 4 consecutive n
      int b = m0 >> 12, n0 = m0 & 4095;
#pragma unroll
      for (int j = 0; j < 4; ++j) {
        int jcl = bn * 128 + wc + j * 16 + l16;      // 0..511 within v region
        int h = (jcl >> 6) & 7, hd = jcl & 63;
        int bh = (b << 3) | h;
        ushort4 pk;
        pk.x = f2bfu(acc[i][j][0]); pk.y = f2bfu(acc[i][j][1]);
        pk.z = f2bfu(acc[i][j][2]); pk.w = f2bfu(acc[i][j][3]);
        *(ushort4*)(vt + ((size_t)bh * HDIM + hd) * SEQ + n0) = pk;
      }
    }
  }
}

// ---------------------------------------------------------------------------
// Kernel 3: flash attention — EXACT R10 structure (proven 99.6 us, no spill).
// S^T formulation, key-split wave pairs, XCD-local grid, register-P PV via
// 16x16x16 MFMA. 128-key tiles, jh=4 (jh=8 in R11 blew hoisted-K-frag VGPR
// pressure -> 13-dword/kt scratch spill, 396MB FETCH — do not re-widen).
// LDS = Ks 16K + Vs 16K + Om 32K + Lb 2K = 66K -> 2 blocks/CU, 16 waves/CU.
// ---------------------------------------------------------------------------
__global__ __launch_bounds__(512, 4) void attn_kernel(
    const uint16_t* __restrict__ qd, const uint16_t* __restrict__ kd,
    const uint16_t* __restrict__ vt, uint16_t* __restrict__ ao) {
  __shared__ __align__(16) uint16_t Ks[128 * 64];    // [key][d], chunk c^=(row&7)
  __shared__ __align__(16) uint16_t Vs[64 * 128];    // [d][key], chunk c^=(row&15)
  __shared__ __align__(16) f32x4 Om[4][8][64];       // pair-merge O buffer, 32KB
  __shared__ __align__(16) float2 Lb[4][64];         // pair-merge lsum, 2KB

  const int tid = threadIdx.x, lane = tid & 63, wave = tid >> 6;  // wave 0..7
  const int quad = lane >> 4, l16 = lane & 15;
  const int pair = wave >> 1, khalf = wave & 1;
  const int qt = blockIdx.x >> 4, bh = blockIdx.x & 15;   // XCD-local bh
  const size_t base_qk = (size_t)bh * SEQ * HDIM;    // [bh][n][d]
  const size_t base_v  = (size_t)bh * HDIM * SEQ;    // [bh][d][n]
  const int sw7 = l16 & 7;

  // Q fragments straight from global (one-time, L2-resident): B-op of K·Q^T
  bf16x8 qf[2][2];
#pragma unroll
  for (int it2 = 0; it2 < 2; ++it2)
#pragma unroll
    for (int kh = 0; kh < 2; ++kh)
      qf[it2][kh] = *(const bf16x8*)(qd + base_qk +
          (size_t)(qt * 128 + pair * 32 + it2 * 16 + l16) * HDIM + kh * 32 + quad * 8);

  f32x4 O[2][4];            // partial over this wave's keys
  float lsum[2] = {0.f, 0.f};
#pragma unroll
  for (int a = 0; a < 2; ++a)
#pragma unroll
    for (int d = 0; d < 4; ++d) O[a][d] = f32x4{0.f, 0.f, 0.f, 0.f};

  for (int kt = 0; kt < SEQ / 128; ++kt) {
    // stage K [128][64] and Vt [64][128], both chunk-swizzled (512 thr, 2 iters)
#pragma unroll
    for (int it = 0; it < 2; ++it) {
      int L = it * 512 + tid;
      int ldsoff = (it * 512 + (tid & ~63)) * 16;
      int rk = L >> 3, ck = L & 7;
      int gck = ck ^ (rk & 7);
      gld16((const char*)kd + (base_qk + (size_t)(kt * 128 + rk) * HDIM) * 2 + gck * 16,
            (char*)Ks + ldsoff);
      int rv = L >> 4, cv = L & 15;
      int gcv = cv ^ (rv & 15);
      gld16((const char*)vt + (base_v + (size_t)rv * SEQ + (size_t)kt * 128) * 2 + gcv * 16,
            (char*)Vs + ldsoff);
    }
    __syncthreads();

    // S^T = K·Q^T for this wave's 64 keys (4 key-16-blocks)
    f32x4 P[4][2];
#pragma unroll
    for (int jh = 0; jh < 4; ++jh) {
      int jf = khalf * 4 + jh;
      const uint16_t* krow = Ks + (jf * 16 + l16) * 64;
      bf16x8 kf0 = *(const bf16x8*)(krow + ((quad ^ sw7) * 8));
      bf16x8 kf1 = *(const bf16x8*)(krow + (((4 + quad) ^ sw7) * 8));
#pragma unroll
      for (int it2 = 0; it2 < 2; ++it2) {
        f32x4 s = f32x4{0.f, 0.f, 0.f, 0.f};
        s = mfma16(kf0, qf[it2][0], s);
        s = mfma16(kf1, qf[it2][1], s);
        P[jh][it2] = s;
      }
    }

    // exp2 + pack -> B-frag in registers; PV via 16x16x16 (A = V b64 frags)
#pragma unroll
    for (int jh = 0; jh < 4; ++jh) {
      bf16x4 pb[2];
#pragma unroll
      for (int it2 = 0; it2 < 2; ++it2) {
        float p0 = EXP2F(P[jh][it2][0]);
        float p1 = EXP2F(P[jh][it2][1]);
        float p2 = EXP2F(P[jh][it2][2]);
        float p3 = EXP2F(P[jh][it2][3]);
        lsum[it2] += (p0 + p1) + (p2 + p3);
        uint32_t a0 = __builtin_bit_cast(uint32_t, p0) + 0x8000u;
        uint32_t a1 = __builtin_bit_cast(uint32_t, p1) + 0x8000u;
        uint32_t a2 = __builtin_bit_cast(uint32_t, p2) + 0x8000u;
        uint32_t a3 = __builtin_bit_cast(uint32_t, p3) + 0x8000u;
        u32x2 pk;
        pk.x = (a0 >> 16) | (a1 & 0xFFFF0000u);   // [bf16(p0), bf16(p1)]
        pk.y = (a2 >> 16) | (a3 & 0xFFFF0000u);   // [bf16(p2), bf16(p3)]
        pb[it2] = __builtin_bit_cast(bf16x4, pk);
      }
      // A-frag: V^T[dl*16+l16][khalf*64 + jh*16 + quad*4 + j], j=0..3 (8B)
      int c = khalf * 8 + jh * 2 + (quad >> 1);
      int coff = ((c ^ l16) * 16) + (quad & 1) * 8;
#pragma unroll
      for (int dl = 0; dl < 4; ++dl) {
        bf16x4 va = *(const bf16x4*)((const char*)Vs + (dl * 16 + l16) * 256 + coff);
#pragma unroll
        for (int it2 = 0; it2 < 2; ++it2)
          O[it2][dl] = mfma16x16(va, pb[it2], O[it2][dl]);
      }
    }
    __syncthreads();
  }

  // merge partial O / lsum across the wave pair (even wave -> LDS, odd reads)
  if (!(wave & 1)) {
#pragma unroll
    for (int it2 = 0; it2 < 2; ++it2)
#pragma unroll
      for (int dl = 0; dl < 4; ++dl)
        Om[pair][it2 * 4 + dl][lane] = O[it2][dl];
    Lb[pair][lane] = make_float2(lsum[0], lsum[1]);
  }
  __syncthreads();
  if (wave & 1) {
    float2 lp = Lb[pair][lane];
    lsum[0] += lp.x; lsum[1] += lp.y;
#pragma unroll
    for (int it2 = 0; it2 < 2; ++it2)
#pragma unroll
      for (int dl = 0; dl < 4; ++dl)
        O[it2][dl] += Om[pair][it2 * 4 + dl][lane];

    const int b = bh >> 3, h = bh & 7;
#pragma unroll
    for (int it2 = 0; it2 < 2; ++it2) {
      float l = lsum[it2];
      l += __shfl_xor(l, 16);
      l += __shfl_xor(l, 32);
      float inv = 1.0f / l;
      int q = qt * 128 + pair * 32 + it2 * 16 + l16;
      size_t rowbase = ((size_t)(b * SEQ + q)) * DIMM + h * HDIM;
#pragma unroll
      for (int dl = 0; dl < 4; ++dl) {
        ushort4 pk;
        pk.x = f2bfu(O[it2][dl][0] * inv);
        pk.y = f2bfu(O[it2][dl][1] * inv);
        pk.z = f2bfu(O[it2][dl][2] * inv);
        pk.w = f2bfu(O[it2][dl][3] * inv);
        *(ushort4*)(ao + rowbase + dl * 16 + quad * 4) = pk;
      }
    }
  }
}

// ---------------------------------------------------------------------------
// Kernel 4: output projection in C^T orientation: C^T[jc][m] = W_p · AO^T.
// Lane's 4 regs = 4 consecutive out-cols -> float4 store with float4 bias.
// Grid (4, 64).
// ---------------------------------------------------------------------------
__global__ __launch_bounds__(256, 2) void proj_gemm(
    const uint16_t* __restrict__ ao, const uint16_t* __restrict__ wpb,
    const float* __restrict__ bprj, float* __restrict__ out) {
  __shared__ __align__(16) uint16_t As[128 * 32];
  __shared__ __align__(16) uint16_t Bs[128 * 32];
  f32x4 acc[4][4];
#pragma unroll
  for (int i = 0; i < 4; ++i)
#pragma unroll
    for (int j = 0; j < 4; ++j) acc[i][j] = f32x4{0.f, 0.f, 0.f, 0.f};

  gemm_core(wpb, ao, As, Bs, acc, blockIdx.x, blockIdx.y);  // acc rows are jc

  const int lane = threadIdx.x & 63, wave = threadIdx.x >> 6;
  const int quad = lane >> 4, l16 = lane & 15;
  const int wr = (wave & 1) * 64, wc = (wave >> 1) * 64;
#pragma unroll
  for (int i = 0; i < 4; ++i) {
    int jc0 = blockIdx.x * 128 + wr + i * 16 + quad * 4;  // 4 consecutive cols
    float4 b4 = *(const float4*)(bprj + jc0);
#pragma unroll
    for (int j = 0; j < 4; ++j) {
      int m = blockIdx.y * 128 + wc + j * 16 + l16;
      float4 o;
      o.x = acc[i][j][0] + b4.x; o.y = acc[i][j][1] + b4.y;
      o.z = acc[i][j][2] + b4.z; o.w = acc[i][j][3] + b4.w;
      *(float4*)(out + (size_t)m * DIMM + jc0) = o;
    }
  }
}

// ---------------------------------------------------------------------------
extern "C" void kernel_launch(void* const* d_in, const int* in_sizes, int n_in,
                              void* d_out, int out_size, void* d_ws, size_t ws_size,
                              hipStream_t stream) {
  const float* x     = (const float*)d_in[0];
  const float* wqkv  = (const float*)d_in[1];
  const float* wproj = (const float*)d_in[2];
  const float* bproj = (const float*)d_in[3];

  char* ws = (char*)d_ws;
  uint16_t* xb  = (uint16_t*)(ws + 0);          //  8,388,608  x bf16 [8192][512]
  uint16_t* wqb = (uint16_t*)(ws + 8388608);    //  1,572,864  w_qkv bf16 [1536][512]
  uint16_t* wpb = (uint16_t*)(ws + 9961472);    //    524,288  w_proj bf16 [512][512]
  uint16_t* qd  = (uint16_t*)(ws + 10485760);   //  8,388,608  q bf16 [16][4096][64] (scaled)
  uint16_t* kd  = (uint16_t*)(ws + 18874368);   //  8,388,608  k bf16 [16][4096][64]
  uint16_t* vt  = (uint16_t*)(ws + 27262976);   //  8,388,608  v bf16 [16][64][4096]
  uint16_t* ao  = (uint16_t*)(ws + 35651584);   //  8,388,608  attn out bf16 [8192][512]

  cvt_kernel<<<(X4 + Q4 + P4) / 256, 256, 0, stream>>>(x, wqkv, wproj, xb, wqb, wpb);
  qkv_gemm2<<<768, 256, 0, stream>>>(xb, wqb, qd, kd, vt);
  attn_kernel<<<512, 512, 0, stream>>>(qd, kd, vt, ao);
  proj_gemm<<<dim3(4, 64), 256, 0, stream>>>(ao, wpb, bproj, (float*)d_out);
}